// Round 9
// baseline (74.406 us; speedup 1.0000x reference)
//
#include <hip/hip_runtime.h>
#include <math.h>

#define NB 16      // batches
#define NN 1024    // visual tokens
#define ND 768     // feature dim
#define NT 256     // text tokens
#define NSEL 16    // selections
#define NC 64      // greedy candidate set (global top-64 by initial di2s)

typedef __attribute__((ext_vector_type(8))) short short8;
typedef __attribute__((ext_vector_type(4))) float f32x4;
typedef __attribute__((ext_vector_type(8))) unsigned short ushort8v;
typedef unsigned long long u64;

// ---- device scratch (every read dominated by a same-launch write) ----
__device__ __align__(16) float g_invv[NB*NN];
__device__ __align__(16) float g_diagv[NB*NN];
__device__ __align__(16) float g_mrawp[NB*NN*2];  // per-128-text-half rowmax
// fragment-order pre-split text: unit(b,th,s,h,ct,lane) of 16B (8 bf16); s = 32-k step
__device__ __align__(16) ushort8v g_tf[NB*2*24*2*8*64];

__device__ __forceinline__ unsigned short f2bf(float x) {
    unsigned u = __float_as_uint(x);
    return (unsigned short)((u + 0x7FFFu + ((u >> 16) & 1u)) >> 16);
}
__device__ __forceinline__ float bf2f(unsigned short h) {
    return __uint_as_float(((unsigned)h) << 16);
}
__device__ __forceinline__ size_t tfidx(int b, int th, int s, int h, int ct, int lane) {
    return ((((size_t)(b*2 + th)*24 + s)*2 + h)*8 + ct)*64 + lane;
}

// ---------------- K1: text norms + bf16 hi/lo split -> FRAGMENT-ORDER global ----------------
__global__ __launch_bounds__(256) void ktxt(const float* __restrict__ txt) {
    int gw = (blockIdx.x * 256 + threadIdx.x) >> 6;   // row 0..NB*NT-1
    int l  = threadIdx.x & 63;
    int b  = gw >> 8, r = gw & 255;
    int th = r >> 7, ct = (r >> 4) & 7, rlo = r & 15;
    const float* row = txt + (size_t)gw * ND;

    float4 x0 = *(const float4*)(row + 8*l);
    float4 y0 = *(const float4*)(row + 8*l + 4);
    float4 x1 = {0,0,0,0}, y1 = {0,0,0,0};
    bool two = (l < 32);
    if (two) {
        x1 = *(const float4*)(row + 512 + 8*l);
        y1 = *(const float4*)(row + 512 + 8*l + 4);
    }
    float s = x0.x*x0.x + x0.y*x0.y + x0.z*x0.z + x0.w*x0.w
            + y0.x*y0.x + y0.y*y0.y + y0.z*y0.z + y0.w*y0.w;
    if (two) s += x1.x*x1.x + x1.y*x1.y + x1.z*x1.z + x1.w*x1.w
                + y1.x*y1.x + y1.y*y1.y + y1.z*y1.z + y1.w*y1.w;
    #pragma unroll
    for (int off = 32; off; off >>= 1) s += __shfl_xor(s, off);
    float inv = 1.0f / (sqrtf(s) + 1e-6f);

    int kslot = l & 3;
    int lane  = kslot*16 + rlo;
    {   // chunk 0: e0 = 8l, s-step = l>>2
        int st = l >> 2;
        float a[8] = {x0.x, x0.y, x0.z, x0.w, y0.x, y0.y, y0.z, y0.w};
        ushort8v hh, ll;
        #pragma unroll
        for (int j = 0; j < 8; j++) {
            float v = a[j] * inv;
            hh[j] = f2bf(v);
            ll[j] = f2bf(v - bf2f(hh[j]));
        }
        g_tf[tfidx(b, th, st, 0, ct, lane)] = hh;
        g_tf[tfidx(b, th, st, 1, ct, lane)] = ll;
    }
    if (two) {  // chunk 1: e0 = 512+8l, s-step = 16 + (l>>2)
        int st = 16 + (l >> 2);
        float a[8] = {x1.x, x1.y, x1.z, x1.w, y1.x, y1.y, y1.z, y1.w};
        ushort8v hh, ll;
        #pragma unroll
        for (int j = 0; j < 8; j++) {
            float v = a[j] * inv;
            hh[j] = f2bf(v);
            ll[j] = f2bf(v - bf2f(hh[j]));
        }
        g_tf[tfidx(b, th, st, 0, ct, lane)] = hh;
        g_tf[tfidx(b, th, st, 1, ct, lane)] = ll;
    }
}

// ---------------- K2 v10: v9 + depth-2 A prefetch (memory-latency exposure fix) ----------------
// Post-mortem v9: halving steps/barriers bought ~0.5us -> fixed-convoy model falsified.
// All on-chip knobs (MFMA -25%, LDS -50%, occupancy x4, conv-ahead, barriers /2) are
// null. Remaining suspect: A-chain memory-latency EXPOSURE under a contended memory
// system (harness 256MB fills run at 6.8TB/s = 85% HBM adjacent to our kernels; under
// contention A-load latency ~2-3k cyc vs v9's one-step ~1.6k cyc slack -> ~1k cyc
// exposed per step regardless of per-step work = every null explained). v10: ping-pong
// two A register sets; at step S issue A(S+2) (after conv reads the set it overwrites).
// vmcnt accounting (in-order): entering S outstanding = A(S+1)(4); + STAGE(S+1)(8) +
// A(S+2)(4) = 16; end-of-S vmcnt(4) keeps exactly A(S+2), drains A(S+1)+STAGE(S+1)
// before the barrier (same cross-wave guarantee as v9). Prologue: A(0), STAGE(0), A(1)
// -> vmcnt(4). Step-10 boundary: vmcnt(0) (no A(12); vmcnt(4) would leave 4 STAGE(11)
// writes in flight = the v8 bug class). Fully unrolled so A-set indexing is static.
// Bit-exactness vs v9: conv order A(0..11) sub-k0,sub-k1 = k-blocks 0..23 (same ss
// chain); MFMA sequence per output unchanged; epilogue/kfinal/ktxt identical.
__global__ __launch_bounds__(256, 2) void krel(const float* __restrict__ vis) {
    int bid = blockIdx.x;
    int lid = (bid & 7) * 64 + (bid >> 3);   // XCD-grouped logical id (bijective, 512 = 8x64)
    int b   = lid >> 5;
    int mt  = (lid >> 1) & 15;
    int th  = lid & 1;
    int t   = threadIdx.x;
    int w   = t >> 6, l = t & 63;

    __shared__ __align__(16) ushort8v Bfrag[2][2][2][8][64];  // [buf][sub-k][hi/lo][ct][lane], 64KB

    f32x4 acc[8];
    #pragma unroll
    for (int ct = 0; ct < 8; ct++) acc[ct] = (f32x4){0.f, 0.f, 0.f, 0.f};

    // A fragment: row mt*64 + w*16 + (l&15), k-slot (l>>4)*8
    int arow = mt*64 + w*16 + (l & 15);
    int akq  = (l >> 4) * 8;
    const float* Ap = vis + ((size_t)(b*NN + arow))*ND + akq;

    // B staging: wave w issues chunks c = w*8..w*8+7; c -> (sub = c>>4, h = (c>>3)&1, ct = c&7)
    const ushort8v* Bbase = g_tf + tfidx(b, th, 0, 0, 0, 0);

    #define STAGE(S, P)                                                          \
        {                                                                        \
            _Pragma("unroll")                                                    \
            for (int q = 0; q < 8; q++) {                                        \
                int c   = w*8 + q;                                               \
                int sub = c >> 4, h = (c >> 3) & 1, ct = c & 7;                  \
                const ushort8v* gsrc = Bbase + (((size_t)((S)*2 + sub)*2 + h)*8 + ct)*64 + l; \
                __builtin_amdgcn_global_load_lds(                                \
                    (const __attribute__((address_space(1))) void*)gsrc,         \
                    (__attribute__((address_space(3))) void*)&Bfrag[P][sub][h][ct][0],\
                    16, 0, 0);                                                   \
            }                                                                    \
        }

    #define CONV(AX, AY, AH, AL, SS)                                             \
        {                                                                        \
            float av_[8] = {AX.x, AX.y, AX.z, AX.w, AY.x, AY.y, AY.z, AY.w};     \
            ushort8v hh_, ll_;                                                   \
            _Pragma("unroll")                                                    \
            for (int j = 0; j < 8; j++) {                                        \
                hh_[j] = f2bf(av_[j]);                                           \
                ll_[j] = f2bf(av_[j] - bf2f(hh_[j]));                            \
                SS = fmaf(av_[j], av_[j], SS);                                   \
            }                                                                    \
            AH = *(short8*)&hh_;                                                 \
            AL = *(short8*)&ll_;                                                 \
        }

    // two A register sets (ping-pong by step parity); x,y = sub-k0; z,w = sub-k1
    float4 A0x, A0y, A0z, A0w, A1x, A1y, A1z, A1w;

    // prologue: A(0) -> set0; STAGE(0); A(1) -> set1; vmcnt(4) keeps A(1) in flight
    A0x = *(const float4*)(Ap);
    A0y = *(const float4*)(Ap + 4);
    A0z = *(const float4*)(Ap + 32);
    A0w = *(const float4*)(Ap + 36);
    asm volatile("" ::: "memory");
    STAGE(0, 0);
    asm volatile("" ::: "memory");
    A1x = *(const float4*)(Ap + 64);
    A1y = *(const float4*)(Ap + 68);
    A1z = *(const float4*)(Ap + 96);
    A1w = *(const float4*)(Ap + 100);
    asm volatile("s_waitcnt vmcnt(4) lgkmcnt(0)" ::: "memory");
    __builtin_amdgcn_s_barrier();
    __builtin_amdgcn_sched_barrier(0);
    float ss = 0.f;

    #define STEP(S)                                                              \
        {                                                                        \
            if ((S) < 11) STAGE((S) + 1, ((S) + 1) & 1);                         \
            asm volatile("" ::: "memory");                                       \
            short8 ah0, al0, ah1, al1;                                           \
            if constexpr (((S) & 1) == 0) {                                      \
                CONV(A0x, A0y, ah0, al0, ss);                                    \
                CONV(A0z, A0w, ah1, al1, ss);                                    \
            } else {                                                             \
                CONV(A1x, A1y, ah0, al0, ss);                                    \
                CONV(A1z, A1w, ah1, al1, ss);                                    \
            }                                                                    \
            if ((S) < 10) {  /* issue A(S+2) into the set conv just consumed */  \
                const float* ap2 = Ap + ((S) + 2) * 64;                          \
                if constexpr (((S) & 1) == 0) {                                  \
                    A0x = *(const float4*)(ap2);                                 \
                    A0y = *(const float4*)(ap2 + 4);                             \
                    A0z = *(const float4*)(ap2 + 32);                            \
                    A0w = *(const float4*)(ap2 + 36);                            \
                } else {                                                         \
                    A1x = *(const float4*)(ap2);                                 \
                    A1y = *(const float4*)(ap2 + 4);                             \
                    A1z = *(const float4*)(ap2 + 32);                            \
                    A1w = *(const float4*)(ap2 + 36);                            \
                }                                                                \
            }                                                                    \
            _Pragma("unroll")                                                    \
            for (int ct = 0; ct < 8; ct++) {                                     \
                short8 bh = *(const short8*)&Bfrag[(S) & 1][0][0][ct][l];        \
                short8 bl = *(const short8*)&Bfrag[(S) & 1][0][1][ct][l];        \
                acc[ct] = __builtin_amdgcn_mfma_f32_16x16x32_bf16(ah0, bh, acc[ct], 0, 0, 0); \
                acc[ct] = __builtin_amdgcn_mfma_f32_16x16x32_bf16(al0, bh, acc[ct], 0, 0, 0); \
                acc[ct] = __builtin_amdgcn_mfma_f32_16x16x32_bf16(ah0, bl, acc[ct], 0, 0, 0); \
            }                                                                    \
            _Pragma("unroll")                                                    \
            for (int ct = 0; ct < 8; ct++) {                                     \
                short8 bh = *(const short8*)&Bfrag[(S) & 1][1][0][ct][l];        \
                short8 bl = *(const short8*)&Bfrag[(S) & 1][1][1][ct][l];        \
                acc[ct] = __builtin_amdgcn_mfma_f32_16x16x32_bf16(ah1, bh, acc[ct], 0, 0, 0); \
                acc[ct] = __builtin_amdgcn_mfma_f32_16x16x32_bf16(al1, bh, acc[ct], 0, 0, 0); \
                acc[ct] = __builtin_amdgcn_mfma_f32_16x16x32_bf16(ah1, bl, acc[ct], 0, 0, 0); \
            }                                                                    \
            if constexpr ((S) == 10) {                                           \
                asm volatile("s_waitcnt vmcnt(0) lgkmcnt(0)" ::: "memory");      \
            } else if constexpr ((S) < 10) {                                     \
                asm volatile("s_waitcnt vmcnt(4) lgkmcnt(0)" ::: "memory");      \
            }                                                                    \
            if ((S) < 11) {                                                      \
                __builtin_amdgcn_s_barrier();                                    \
                __builtin_amdgcn_sched_barrier(0);                               \
            }                                                                    \
        }

    STEP(0)  STEP(1)  STEP(2)  STEP(3)  STEP(4)  STEP(5)
    STEP(6)  STEP(7)  STEP(8)  STEP(9)  STEP(10) STEP(11)

    #undef STEP
    #undef STAGE
    #undef CONV

    // rowmax over this half's 128 cols (exact; kfinal maxes the 2 halves)
    #pragma unroll
    for (int r = 0; r < 4; r++) {
        float m = acc[0][r];
        #pragma unroll
        for (int ct = 1; ct < 8; ct++) m = fmaxf(m, acc[ct][r]);
        #pragma unroll
        for (int off = 1; off <= 8; off <<= 1) m = fmaxf(m, __shfl_xor(m, off));
        if ((l & 15) == 0)
            g_mrawp[(size_t)(b*NN + mt*64 + w*16 + (l >> 4)*4 + r)*2 + th] = m;
    }

    // vis row sumsq -> invv/diag (same combine tree); only th==0 writes
    ss += __shfl_xor(ss, 16);
    ss += __shfl_xor(ss, 32);
    if (th == 0 && l < 16) {
        int row = mt*64 + w*16 + l;
        float nrm = sqrtf(ss);
        float inv = 1.0f / (nrm + 1e-6f);
        g_invv[b*NN + row] = inv;
        float dd = nrm * inv;
        g_diagv[b*NN + row] = dd * dd;
    }
}

// ---------------- K3: prep + reg-sort top-64 + MFMA Gram + single-wave greedy + gather ----------------
__global__ __launch_bounds__(1024) void kfinal(const float* __restrict__ vis,
                                               float* __restrict__ out) {
    int b = blockIdx.x;
    int t = threadIdx.x;
    int w = t >> 6, l = t & 63;

    __shared__ u64   s_key[NN];
    __shared__ float s_reln[NN];
    __shared__ __align__(16) unsigned short Chi[NC][392], Clo[NC][392];  // K-chunk 384 + pad
    __shared__ float s_S[NC*65];
    __shared__ int   s_sel[NSEL], s_srt[NSEL];
    __shared__ float s_mn[16], s_mx[16], s_b2[2];

    // ---- prep: relevance minmax-normalize, di2s0, key (1 elem/thread) ----
    float m0 = g_mrawp[(size_t)(b*NN + t)*2 + 0];
    float m1 = g_mrawp[(size_t)(b*NN + t)*2 + 1];
    float iv = g_invv[b*NN + t], dd = g_diagv[b*NN + t];
    float rr = fmaxf(m0, m1) * iv;
    float lmin = rr, lmax = rr;
    #pragma unroll
    for (int off = 32; off; off >>= 1) {
        lmin = fminf(lmin, __shfl_xor(lmin, off));
        lmax = fmaxf(lmax, __shfl_xor(lmax, off));
    }
    if (l == 0) { s_mn[w] = lmin; s_mx[w] = lmax; }
    __syncthreads();
    if (t == 0) {
        float mn = s_mn[0], mx = s_mx[0];
        #pragma unroll
        for (int q = 1; q < 16; q++) { mn = fminf(mn, s_mn[q]); mx = fmaxf(mx, s_mx[q]); }
        s_b2[0] = mn; s_b2[1] = mx;
    }
    __syncthreads();
    float mn = s_b2[0], mx = s_b2[1];
    float den = mx - mn + 1e-6f;
    float rn = (rr - mn + 1e-6f) / den;
    float d0 = rn * rn * dd;
    s_reln[t] = rn;
    u64 kreg = ((u64)(~__float_as_uint(d0)) << 10) | (unsigned)t;

    // ---- per-wave in-register bitonic sort (ascending key = descending d0) ----
    #pragma unroll
    for (int k = 2; k <= 64; k <<= 1) {
        #pragma unroll
        for (int j = k >> 1; j > 0; j >>= 1) {
            u64 part = __shfl_xor(kreg, j);
            bool takeMin = ((l & k) == 0) == ((l & j) == 0);
            kreg = takeMin ? (kreg < part ? kreg : part) : (kreg < part ? part : kreg);
        }
    }
    // ---- symmetric tournament merge: 4 rounds, every wave ends with global top-64 ----
    #pragma unroll
    for (int rnd = 0; rnd < 4; rnd++) {
        int dstp = 8 >> rnd;
        s_key[w*64 + l] = kreg;
        __syncthreads();
        u64 other = s_key[(w ^ dstp)*64 + (63 - l)];
        u64 m = (kreg < other) ? kreg : other;     // 64 smallest of union (bitonic)
        #pragma unroll
        for (int j = 32; j > 0; j >>= 1) {         // ascending clean
            u64 part = __shfl_xor(m, j);
            bool takeMin = ((l & j) == 0);
            m = takeMin ? (m < part ? m : part) : (m < part ? part : m);
        }
        kreg = m;
        __syncthreads();
    }

    // lane l of every wave: l-th best candidate
    int   gid = (int)(kreg & 1023u);
    float d0v = __uint_as_float(~(unsigned)(kreg >> 10));

    // ---- Gram S = vn_c . vn_c^T via bf16x3 MFMA, 2 chunks of K=384 ----
    f32x4 acc = (f32x4){0.f, 0.f, 0.f, 0.f};
    int ar0 = (w >> 2) * 16, bc0 = (w & 3) * 16;
    int cr  = (w << 2) + (l >> 4);                 // candidate row this thread stages
    int sgid = __shfl(gid, cr);
    float sc = g_invv[b*NN + sgid];
    const float* srcrow = vis + (size_t)(b*NN + sgid)*ND + (l & 15)*24;

    for (int c = 0; c < 2; c++) {
        __syncthreads();
        int kb = (l & 15) * 24;
        #pragma unroll
        for (int q = 0; q < 3; q++) {
            float4 x = *(const float4*)(srcrow + c*384 + q*8);
            float4 y = *(const float4*)(srcrow + c*384 + q*8 + 4);
            float av[8] = {x.x, x.y, x.z, x.w, y.x, y.y, y.z, y.w};
            ushort8v hh, ll;
            #pragma unroll
            for (int j = 0; j < 8; j++) {
                float vv = av[j] * sc;
                hh[j] = f2bf(vv);
                ll[j] = f2bf(vv - bf2f(hh[j]));
            }
            *(ushort8v*)&Chi[cr][kb + q*8] = hh;
            *(ushort8v*)&Clo[cr][kb + q*8] = ll;
        }
        __syncthreads();
        #pragma unroll
        for (int ks = 0; ks < 12; ks++) {
            int ko = ks*32 + (l >> 4)*8;
            short8 ah = *(const short8*)&Chi[ar0 + (l & 15)][ko];
            short8 al = *(const short8*)&Clo[ar0 + (l & 15)][ko];
            short8 bh = *(const short8*)&Chi[bc0 + (l & 15)][ko];
            short8 bl = *(const short8*)&Clo[bc0 + (l & 15)][ko];
            acc = __builtin_amdgcn_mfma_f32_16x16x32_bf16(ah, bh, acc, 0, 0, 0);
            acc = __builtin_amdgcn_mfma_f32_16x16x32_bf16(al, bh, acc, 0, 0, 0);
            acc = __builtin_amdgcn_mfma_f32_16x16x32_bf16(ah, bl, acc, 0, 0, 0);
        }
    }
    #pragma unroll
    for (int r = 0; r < 4; r++)
        s_S[(ar0 + (l >> 4)*4 + r)*65 + bc0 + (l & 15)] = acc[r];
    __syncthreads();

    // ---- single-wave greedy: lane = candidate, zero barriers, all state in registers ----
    if (w == 0) {
        float di  = d0v;
        int   gd  = gid;
        float rel = s_reln[gid];
        float ownc[NSEL];
        #pragma unroll
        for (int i = 0; i < NSEL; i++) {
            float vq = fmaxf(di, 1e-12f);
            int   gq = gd;
            int   cq = l;
            #pragma unroll
            for (int off = 32; off; off >>= 1) {
                float vo = __shfl_xor(vq, off);
                int   go = __shfl_xor(gq, off);
                int   co = __shfl_xor(cq, off);
                if (vo > vq || (vo == vq && go < gq)) { vq = vo; gq = go; cq = co; }
            }
            float dj   = __shfl(di, cq);
            float relj = __shfl(rel, cq);
            float denom = sqrtf(fmaxf(dj, 1e-12f)) + 1e-8f;
            if (l == 0) s_sel[i] = gq;

            float cov = 0.f;
            #pragma unroll
            for (int q = 0; q < i; q++)
                cov = fmaf(ownc[q], __shfl(ownc[q], cq), cov);

            float sim = s_S[l*65 + cq];
            float kj  = rel * relj * sim;
            float eis = (kj - cov) / denom;
            ownc[i] = eis;
            di = di - eis * eis;
            if (l == cq) di = -__builtin_inff();
        }
    }
    __syncthreads();

    // ---- sort selected indices; wave w gathers output row w ----
    if (t == 0) {
        int vv[16];
        #pragma unroll
        for (int q = 0; q < 16; q++) vv[q] = s_sel[q];
        for (int a = 1; a < 16; a++) {
            int key = vv[a]; int p2 = a - 1;
            while (p2 >= 0 && vv[p2] > key) { vv[p2+1] = vv[p2]; p2--; }
            vv[p2+1] = key;
        }
        #pragma unroll
        for (int q = 0; q < 16; q++) s_srt[q] = vv[q];
    }
    __syncthreads();
    {
        int idx = s_srt[w];
        const float* src = vis + (size_t)(b*NN + idx)*ND + l*12;
        float*       dst = out + (size_t)(b*NSEL + w)*ND + l*12;
        float4 x = *(const float4*)(src);
        float4 y = *(const float4*)(src + 4);
        float4 z = *(const float4*)(src + 8);
        *(float4*)(dst)     = x;
        *(float4*)(dst + 4) = y;
        *(float4*)(dst + 8) = z;
    }
}

extern "C" void kernel_launch(void* const* d_in, const int* in_sizes, int n_in,
                              void* d_out, int out_size, void* d_ws, size_t ws_size,
                              hipStream_t stream) {
    (void)in_sizes; (void)n_in; (void)d_ws; (void)ws_size; (void)out_size;
    const float* vis = (const float*)d_in[0];
    const float* txt = (const float*)d_in[1];
    float* out = (float*)d_out;

    ktxt  <<<dim3((NB*NT)/4), dim3(256),  0, stream>>>(txt);
    krel  <<<dim3(512),       dim3(256),  0, stream>>>(vis);
    kfinal<<<dim3(NB),        dim3(1024), 0, stream>>>(vis, out);
}

// Round 10
// 70.837 us; speedup vs baseline: 1.0504x; 1.0504x over previous
//
#include <hip/hip_runtime.h>
#include <math.h>

#define NB 16      // batches
#define NN 1024    // visual tokens
#define ND 768     // feature dim
#define NT 256     // text tokens
#define NSEL 16    // selections
#define NC 64      // greedy candidate set (global top-64 by initial di2s)

typedef __attribute__((ext_vector_type(8))) short short8;
typedef __attribute__((ext_vector_type(4))) float f32x4;
typedef __attribute__((ext_vector_type(8))) unsigned short ushort8v;
typedef unsigned long long u64;

// ---- device scratch (every read dominated by a same-launch write) ----
__device__ __align__(16) float g_invv[NB*NN];
__device__ __align__(16) float g_diagv[NB*NN];
__device__ __align__(16) float g_mrawp[NB*NN*2];  // per-128-text-half rowmax
// fragment-order pre-split text: unit(b,th,s,h,ct,lane) of 16B (8 bf16); s = 32-k step
__device__ __align__(16) ushort8v g_tf[NB*2*24*2*8*64];

__device__ __forceinline__ unsigned short f2bf(float x) {
    unsigned u = __float_as_uint(x);
    return (unsigned short)((u + 0x7FFFu + ((u >> 16) & 1u)) >> 16);
}
__device__ __forceinline__ float bf2f(unsigned short h) {
    return __uint_as_float(((unsigned)h) << 16);
}
__device__ __forceinline__ size_t tfidx(int b, int th, int s, int h, int ct, int lane) {
    return ((((size_t)(b*2 + th)*24 + s)*2 + h)*8 + ct)*64 + lane;
}

// ---------------- K1: text norms + bf16 hi/lo split -> FRAGMENT-ORDER global ----------------
__global__ __launch_bounds__(256) void ktxt(const float* __restrict__ txt) {
    int gw = (blockIdx.x * 256 + threadIdx.x) >> 6;   // row 0..NB*NT-1
    int l  = threadIdx.x & 63;
    int b  = gw >> 8, r = gw & 255;
    int th = r >> 7, ct = (r >> 4) & 7, rlo = r & 15;
    const float* row = txt + (size_t)gw * ND;

    float4 x0 = *(const float4*)(row + 8*l);
    float4 y0 = *(const float4*)(row + 8*l + 4);
    float4 x1 = {0,0,0,0}, y1 = {0,0,0,0};
    bool two = (l < 32);
    if (two) {
        x1 = *(const float4*)(row + 512 + 8*l);
        y1 = *(const float4*)(row + 512 + 8*l + 4);
    }
    float s = x0.x*x0.x + x0.y*x0.y + x0.z*x0.z + x0.w*x0.w
            + y0.x*y0.x + y0.y*y0.y + y0.z*y0.z + y0.w*y0.w;
    if (two) s += x1.x*x1.x + x1.y*x1.y + x1.z*x1.z + x1.w*x1.w
                + y1.x*y1.x + y1.y*y1.y + y1.z*y1.z + y1.w*y1.w;
    #pragma unroll
    for (int off = 32; off; off >>= 1) s += __shfl_xor(s, off);
    float inv = 1.0f / (sqrtf(s) + 1e-6f);

    int kslot = l & 3;
    int lane  = kslot*16 + rlo;
    {   // chunk 0: e0 = 8l, s-step = l>>2
        int st = l >> 2;
        float a[8] = {x0.x, x0.y, x0.z, x0.w, y0.x, y0.y, y0.z, y0.w};
        ushort8v hh, ll;
        #pragma unroll
        for (int j = 0; j < 8; j++) {
            float v = a[j] * inv;
            hh[j] = f2bf(v);
            ll[j] = f2bf(v - bf2f(hh[j]));
        }
        g_tf[tfidx(b, th, st, 0, ct, lane)] = hh;
        g_tf[tfidx(b, th, st, 1, ct, lane)] = ll;
    }
    if (two) {  // chunk 1: e0 = 512+8l, s-step = 16 + (l>>2)
        int st = 16 + (l >> 2);
        float a[8] = {x1.x, x1.y, x1.z, x1.w, y1.x, y1.y, y1.z, y1.w};
        ushort8v hh, ll;
        #pragma unroll
        for (int j = 0; j < 8; j++) {
            float v = a[j] * inv;
            hh[j] = f2bf(v);
            ll[j] = f2bf(v - bf2f(hh[j]));
        }
        g_tf[tfidx(b, th, st, 0, ct, lane)] = hh;
        g_tf[tfidx(b, th, st, 1, ct, lane)] = ll;
    }
}

// ---------------- K2 v11: depth-2 A prefetch, DE-SPILLED (v10 retest) ----------------
// Post-mortem v10: VGPR pinned at the launch_bounds(256,2) cap of 128 + WRITE_SIZE
// 8.9MB / FETCH +4.5MB = scratch-spill signature -> round 8 tested spill cost, not the
// latency theory. LDS (64KB/block) already caps occupancy at 2 blocks/CU (needs only
// VGPR<=256), so the cap was pointless. v11 = same schedule, two fixes: (a) no min-waves
// clause -> allocator free to ~110-140 regs, zero spill, identical occupancy; (b) rolled
// loop over step-PAIRS (6 iters, parity-static A-set ping-pong via macro args) instead
// of 12x full unroll -> less live-range bloat. vmcnt accounting unchanged: entering step
// S outstanding = A(S+1)(4); issue STAGE(S+1)(8) then A(S+2)(4); end-of-S vmcnt(4)
// drains A(S+1)+STAGE(S+1) across all waves before the barrier (v9's cross-wave
// guarantee); S=10 uses vmcnt(0) (no A(12)). Bit-exact vs v9: conv order A(0..11) x
// (sub-k0,sub-k1) = k-blocks 0..23; MFMA per-output sequence, trees, epilogue unchanged.
__global__ __launch_bounds__(256) void krel(const float* __restrict__ vis) {
    int bid = blockIdx.x;
    int lid = (bid & 7) * 64 + (bid >> 3);   // XCD-grouped logical id (bijective, 512 = 8x64)
    int b   = lid >> 5;
    int mt  = (lid >> 1) & 15;
    int th  = lid & 1;
    int t   = threadIdx.x;
    int w   = t >> 6, l = t & 63;

    __shared__ __align__(16) ushort8v Bfrag[2][2][2][8][64];  // [buf][sub-k][hi/lo][ct][lane], 64KB

    f32x4 acc[8];
    #pragma unroll
    for (int ct = 0; ct < 8; ct++) acc[ct] = (f32x4){0.f, 0.f, 0.f, 0.f};

    // A fragment: row mt*64 + w*16 + (l&15), k-slot (l>>4)*8
    int arow = mt*64 + w*16 + (l & 15);
    int akq  = (l >> 4) * 8;
    const float* Ap = vis + ((size_t)(b*NN + arow))*ND + akq;

    // B staging: wave w issues chunks c = w*8..w*8+7; c -> (sub = c>>4, h = (c>>3)&1, ct = c&7)
    const ushort8v* Bbase = g_tf + tfidx(b, th, 0, 0, 0, 0);

    #define STAGE(S, P)                                                          \
        {                                                                        \
            _Pragma("unroll")                                                    \
            for (int q = 0; q < 8; q++) {                                        \
                int c   = w*8 + q;                                               \
                int sub = c >> 4, h = (c >> 3) & 1, ct = c & 7;                  \
                const ushort8v* gsrc = Bbase + (((size_t)((S)*2 + sub)*2 + h)*8 + ct)*64 + l; \
                __builtin_amdgcn_global_load_lds(                                \
                    (const __attribute__((address_space(1))) void*)gsrc,         \
                    (__attribute__((address_space(3))) void*)&Bfrag[P][sub][h][ct][0],\
                    16, 0, 0);                                                   \
            }                                                                    \
        }

    #define CONV(AX, AY, AH, AL, SS)                                             \
        {                                                                        \
            float av_[8] = {AX.x, AX.y, AX.z, AX.w, AY.x, AY.y, AY.z, AY.w};     \
            ushort8v hh_, ll_;                                                   \
            _Pragma("unroll")                                                    \
            for (int j = 0; j < 8; j++) {                                        \
                hh_[j] = f2bf(av_[j]);                                           \
                ll_[j] = f2bf(av_[j] - bf2f(hh_[j]));                            \
                SS = fmaf(av_[j], av_[j], SS);                                   \
            }                                                                    \
            AH = *(short8*)&hh_;                                                 \
            AL = *(short8*)&ll_;                                                 \
        }

    // one full step; A-set registers passed by name (parity-static, rule-#20 safe)
    #define STEPF(S, AX, AY, AZ, AW)                                             \
        {                                                                        \
            if ((S) < 11) STAGE((S) + 1, ((S) + 1) & 1);                         \
            asm volatile("" ::: "memory");                                       \
            short8 ah0, al0, ah1, al1;                                           \
            CONV(AX, AY, ah0, al0, ss);                                          \
            CONV(AZ, AW, ah1, al1, ss);                                          \
            if ((S) < 10) {  /* issue A(S+2) into the set conv just consumed */  \
                const float* ap2 = Ap + ((S) + 2) * 64;                          \
                AX = *(const float4*)(ap2);                                      \
                AY = *(const float4*)(ap2 + 4);                                  \
                AZ = *(const float4*)(ap2 + 32);                                 \
                AW = *(const float4*)(ap2 + 36);                                 \
            }                                                                    \
            _Pragma("unroll")                                                    \
            for (int ct = 0; ct < 8; ct++) {                                     \
                short8 bh = *(const short8*)&Bfrag[(S) & 1][0][0][ct][l];        \
                short8 bl = *(const short8*)&Bfrag[(S) & 1][0][1][ct][l];        \
                acc[ct] = __builtin_amdgcn_mfma_f32_16x16x32_bf16(ah0, bh, acc[ct], 0, 0, 0); \
                acc[ct] = __builtin_amdgcn_mfma_f32_16x16x32_bf16(al0, bh, acc[ct], 0, 0, 0); \
                acc[ct] = __builtin_amdgcn_mfma_f32_16x16x32_bf16(ah0, bl, acc[ct], 0, 0, 0); \
            }                                                                    \
            _Pragma("unroll")                                                    \
            for (int ct = 0; ct < 8; ct++) {                                     \
                short8 bh = *(const short8*)&Bfrag[(S) & 1][1][0][ct][l];        \
                short8 bl = *(const short8*)&Bfrag[(S) & 1][1][1][ct][l];        \
                acc[ct] = __builtin_amdgcn_mfma_f32_16x16x32_bf16(ah1, bh, acc[ct], 0, 0, 0); \
                acc[ct] = __builtin_amdgcn_mfma_f32_16x16x32_bf16(al1, bh, acc[ct], 0, 0, 0); \
                acc[ct] = __builtin_amdgcn_mfma_f32_16x16x32_bf16(ah1, bl, acc[ct], 0, 0, 0); \
            }                                                                    \
            if ((S) == 10) {                                                     \
                asm volatile("s_waitcnt vmcnt(0) lgkmcnt(0)" ::: "memory");      \
            } else if ((S) < 10) {                                               \
                asm volatile("s_waitcnt vmcnt(4) lgkmcnt(0)" ::: "memory");      \
            }                                                                    \
            if ((S) < 11) {                                                      \
                __builtin_amdgcn_s_barrier();                                    \
                __builtin_amdgcn_sched_barrier(0);                               \
            }                                                                    \
        }

    // two A register sets (ping-pong by step parity); x,y = sub-k0; z,w = sub-k1
    float4 A0x, A0y, A0z, A0w, A1x, A1y, A1z, A1w;

    // prologue: A(0) -> set0; STAGE(0); A(1) -> set1; vmcnt(4) keeps A(1) in flight
    A0x = *(const float4*)(Ap);
    A0y = *(const float4*)(Ap + 4);
    A0z = *(const float4*)(Ap + 32);
    A0w = *(const float4*)(Ap + 36);
    asm volatile("" ::: "memory");
    STAGE(0, 0);
    asm volatile("" ::: "memory");
    A1x = *(const float4*)(Ap + 64);
    A1y = *(const float4*)(Ap + 68);
    A1z = *(const float4*)(Ap + 96);
    A1w = *(const float4*)(Ap + 100);
    asm volatile("s_waitcnt vmcnt(4) lgkmcnt(0)" ::: "memory");
    __builtin_amdgcn_s_barrier();
    __builtin_amdgcn_sched_barrier(0);
    float ss = 0.f;

    for (int S2 = 0; S2 < 12; S2 += 2) {
        STEPF(S2,     A0x, A0y, A0z, A0w)
        STEPF(S2 + 1, A1x, A1y, A1z, A1w)
    }

    #undef STEPF
    #undef STAGE
    #undef CONV

    // rowmax over this half's 128 cols (exact; kfinal maxes the 2 halves)
    #pragma unroll
    for (int r = 0; r < 4; r++) {
        float m = acc[0][r];
        #pragma unroll
        for (int ct = 1; ct < 8; ct++) m = fmaxf(m, acc[ct][r]);
        #pragma unroll
        for (int off = 1; off <= 8; off <<= 1) m = fmaxf(m, __shfl_xor(m, off));
        if ((l & 15) == 0)
            g_mrawp[(size_t)(b*NN + mt*64 + w*16 + (l >> 4)*4 + r)*2 + th] = m;
    }

    // vis row sumsq -> invv/diag (same combine tree); only th==0 writes
    ss += __shfl_xor(ss, 16);
    ss += __shfl_xor(ss, 32);
    if (th == 0 && l < 16) {
        int row = mt*64 + w*16 + l;
        float nrm = sqrtf(ss);
        float inv = 1.0f / (nrm + 1e-6f);
        g_invv[b*NN + row] = inv;
        float dd = nrm * inv;
        g_diagv[b*NN + row] = dd * dd;
    }
}

// ---------------- K3: prep + reg-sort top-64 + MFMA Gram + single-wave greedy + gather ----------------
__global__ __launch_bounds__(1024) void kfinal(const float* __restrict__ vis,
                                               float* __restrict__ out) {
    int b = blockIdx.x;
    int t = threadIdx.x;
    int w = t >> 6, l = t & 63;

    __shared__ u64   s_key[NN];
    __shared__ float s_reln[NN];
    __shared__ __align__(16) unsigned short Chi[NC][392], Clo[NC][392];  // K-chunk 384 + pad
    __shared__ float s_S[NC*65];
    __shared__ int   s_sel[NSEL], s_srt[NSEL];
    __shared__ float s_mn[16], s_mx[16], s_b2[2];

    // ---- prep: relevance minmax-normalize, di2s0, key (1 elem/thread) ----
    float m0 = g_mrawp[(size_t)(b*NN + t)*2 + 0];
    float m1 = g_mrawp[(size_t)(b*NN + t)*2 + 1];
    float iv = g_invv[b*NN + t], dd = g_diagv[b*NN + t];
    float rr = fmaxf(m0, m1) * iv;
    float lmin = rr, lmax = rr;
    #pragma unroll
    for (int off = 32; off; off >>= 1) {
        lmin = fminf(lmin, __shfl_xor(lmin, off));
        lmax = fmaxf(lmax, __shfl_xor(lmax, off));
    }
    if (l == 0) { s_mn[w] = lmin; s_mx[w] = lmax; }
    __syncthreads();
    if (t == 0) {
        float mn = s_mn[0], mx = s_mx[0];
        #pragma unroll
        for (int q = 1; q < 16; q++) { mn = fminf(mn, s_mn[q]); mx = fmaxf(mx, s_mx[q]); }
        s_b2[0] = mn; s_b2[1] = mx;
    }
    __syncthreads();
    float mn = s_b2[0], mx = s_b2[1];
    float den = mx - mn + 1e-6f;
    float rn = (rr - mn + 1e-6f) / den;
    float d0 = rn * rn * dd;
    s_reln[t] = rn;
    u64 kreg = ((u64)(~__float_as_uint(d0)) << 10) | (unsigned)t;

    // ---- per-wave in-register bitonic sort (ascending key = descending d0) ----
    #pragma unroll
    for (int k = 2; k <= 64; k <<= 1) {
        #pragma unroll
        for (int j = k >> 1; j > 0; j >>= 1) {
            u64 part = __shfl_xor(kreg, j);
            bool takeMin = ((l & k) == 0) == ((l & j) == 0);
            kreg = takeMin ? (kreg < part ? kreg : part) : (kreg < part ? part : kreg);
        }
    }
    // ---- symmetric tournament merge: 4 rounds, every wave ends with global top-64 ----
    #pragma unroll
    for (int rnd = 0; rnd < 4; rnd++) {
        int dstp = 8 >> rnd;
        s_key[w*64 + l] = kreg;
        __syncthreads();
        u64 other = s_key[(w ^ dstp)*64 + (63 - l)];
        u64 m = (kreg < other) ? kreg : other;     // 64 smallest of union (bitonic)
        #pragma unroll
        for (int j = 32; j > 0; j >>= 1) {         // ascending clean
            u64 part = __shfl_xor(m, j);
            bool takeMin = ((l & j) == 0);
            m = takeMin ? (m < part ? m : part) : (m < part ? part : m);
        }
        kreg = m;
        __syncthreads();
    }

    // lane l of every wave: l-th best candidate
    int   gid = (int)(kreg & 1023u);
    float d0v = __uint_as_float(~(unsigned)(kreg >> 10));

    // ---- Gram S = vn_c . vn_c^T via bf16x3 MFMA, 2 chunks of K=384 ----
    f32x4 acc = (f32x4){0.f, 0.f, 0.f, 0.f};
    int ar0 = (w >> 2) * 16, bc0 = (w & 3) * 16;
    int cr  = (w << 2) + (l >> 4);                 // candidate row this thread stages
    int sgid = __shfl(gid, cr);
    float sc = g_invv[b*NN + sgid];
    const float* srcrow = vis + (size_t)(b*NN + sgid)*ND + (l & 15)*24;

    for (int c = 0; c < 2; c++) {
        __syncthreads();
        int kb = (l & 15) * 24;
        #pragma unroll
        for (int q = 0; q < 3; q++) {
            float4 x = *(const float4*)(srcrow + c*384 + q*8);
            float4 y = *(const float4*)(srcrow + c*384 + q*8 + 4);
            float av[8] = {x.x, x.y, x.z, x.w, y.x, y.y, y.z, y.w};
            ushort8v hh, ll;
            #pragma unroll
            for (int j = 0; j < 8; j++) {
                float vv = av[j] * sc;
                hh[j] = f2bf(vv);
                ll[j] = f2bf(vv - bf2f(hh[j]));
            }
            *(ushort8v*)&Chi[cr][kb + q*8] = hh;
            *(ushort8v*)&Clo[cr][kb + q*8] = ll;
        }
        __syncthreads();
        #pragma unroll
        for (int ks = 0; ks < 12; ks++) {
            int ko = ks*32 + (l >> 4)*8;
            short8 ah = *(const short8*)&Chi[ar0 + (l & 15)][ko];
            short8 al = *(const short8*)&Clo[ar0 + (l & 15)][ko];
            short8 bh = *(const short8*)&Chi[bc0 + (l & 15)][ko];
            short8 bl = *(const short8*)&Clo[bc0 + (l & 15)][ko];
            acc = __builtin_amdgcn_mfma_f32_16x16x32_bf16(ah, bh, acc, 0, 0, 0);
            acc = __builtin_amdgcn_mfma_f32_16x16x32_bf16(al, bh, acc, 0, 0, 0);
            acc = __builtin_amdgcn_mfma_f32_16x16x32_bf16(ah, bl, acc, 0, 0, 0);
        }
    }
    #pragma unroll
    for (int r = 0; r < 4; r++)
        s_S[(ar0 + (l >> 4)*4 + r)*65 + bc0 + (l & 15)] = acc[r];
    __syncthreads();

    // ---- single-wave greedy: lane = candidate, zero barriers, all state in registers ----
    if (w == 0) {
        float di  = d0v;
        int   gd  = gid;
        float rel = s_reln[gid];
        float ownc[NSEL];
        #pragma unroll
        for (int i = 0; i < NSEL; i++) {
            float vq = fmaxf(di, 1e-12f);
            int   gq = gd;
            int   cq = l;
            #pragma unroll
            for (int off = 32; off; off >>= 1) {
                float vo = __shfl_xor(vq, off);
                int   go = __shfl_xor(gq, off);
                int   co = __shfl_xor(cq, off);
                if (vo > vq || (vo == vq && go < gq)) { vq = vo; gq = go; cq = co; }
            }
            float dj   = __shfl(di, cq);
            float relj = __shfl(rel, cq);
            float denom = sqrtf(fmaxf(dj, 1e-12f)) + 1e-8f;
            if (l == 0) s_sel[i] = gq;

            float cov = 0.f;
            #pragma unroll
            for (int q = 0; q < i; q++)
                cov = fmaf(ownc[q], __shfl(ownc[q], cq), cov);

            float sim = s_S[l*65 + cq];
            float kj  = rel * relj * sim;
            float eis = (kj - cov) / denom;
            ownc[i] = eis;
            di = di - eis * eis;
            if (l == cq) di = -__builtin_inff();
        }
    }
    __syncthreads();

    // ---- sort selected indices; wave w gathers output row w ----
    if (t == 0) {
        int vv[16];
        #pragma unroll
        for (int q = 0; q < 16; q++) vv[q] = s_sel[q];
        for (int a = 1; a < 16; a++) {
            int key = vv[a]; int p2 = a - 1;
            while (p2 >= 0 && vv[p2] > key) { vv[p2+1] = vv[p2]; p2--; }
            vv[p2+1] = key;
        }
        #pragma unroll
        for (int q = 0; q < 16; q++) s_srt[q] = vv[q];
    }
    __syncthreads();
    {
        int idx = s_srt[w];
        const float* src = vis + (size_t)(b*NN + idx)*ND + l*12;
        float*       dst = out + (size_t)(b*NSEL + w)*ND + l*12;
        float4 x = *(const float4*)(src);
        float4 y = *(const float4*)(src + 4);
        float4 z = *(const float4*)(src + 8);
        *(float4*)(dst)     = x;
        *(float4*)(dst + 4) = y;
        *(float4*)(dst + 8) = z;
    }
}

extern "C" void kernel_launch(void* const* d_in, const int* in_sizes, int n_in,
                              void* d_out, int out_size, void* d_ws, size_t ws_size,
                              hipStream_t stream) {
    (void)in_sizes; (void)n_in; (void)d_ws; (void)ws_size; (void)out_size;
    const float* vis = (const float*)d_in[0];
    const float* txt = (const float*)d_in[1];
    float* out = (float*)d_out;

    ktxt  <<<dim3((NB*NT)/4), dim3(256),  0, stream>>>(txt);
    krel  <<<dim3(512),       dim3(256),  0, stream>>>(vis);
    kfinal<<<dim3(NB),        dim3(1024), 0, stream>>>(vis, out);
}

// Round 11
// 68.937 us; speedup vs baseline: 1.0793x; 1.0276x over previous
//
#include <hip/hip_runtime.h>
#include <math.h>

#define NB 16      // batches
#define NN 1024    // visual tokens
#define ND 768     // feature dim
#define NT 256     // text tokens
#define NSEL 16    // selections
#define NC 64      // greedy candidate set (global top-64 by initial di2s)

typedef __attribute__((ext_vector_type(8))) short short8;
typedef __attribute__((ext_vector_type(4))) float f32x4;
typedef __attribute__((ext_vector_type(8))) unsigned short ushort8v;
typedef unsigned long long u64;

// ---- device scratch (every read dominated by a same-launch write) ----
__device__ __align__(16) float g_invv[NB*NN];
__device__ __align__(16) float g_diagv[NB*NN];
__device__ __align__(16) float g_mrawp[NB*NN*2];  // per-128-text-half rowmax
// fragment-order pre-split text: unit(b,th,s,h,ct,lane) of 16B (8 bf16); s = 32-k step
__device__ __align__(16) ushort8v g_tf[NB*2*24*2*8*64];

__device__ __forceinline__ unsigned short f2bf(float x) {
    unsigned u = __float_as_uint(x);
    return (unsigned short)((u + 0x7FFFu + ((u >> 16) & 1u)) >> 16);
}
__device__ __forceinline__ float bf2f(unsigned short h) {
    return __uint_as_float(((unsigned)h) << 16);
}
__device__ __forceinline__ size_t tfidx(int b, int th, int s, int h, int ct, int lane) {
    return ((((size_t)(b*2 + th)*24 + s)*2 + h)*8 + ct)*64 + lane;
}

// ---------------- K1: text norms + bf16 hi/lo split -> FRAGMENT-ORDER global ----------------
__global__ __launch_bounds__(256) void ktxt(const float* __restrict__ txt) {
    int gw = (blockIdx.x * 256 + threadIdx.x) >> 6;   // row 0..NB*NT-1
    int l  = threadIdx.x & 63;
    int b  = gw >> 8, r = gw & 255;
    int th = r >> 7, ct = (r >> 4) & 7, rlo = r & 15;
    const float* row = txt + (size_t)gw * ND;

    float4 x0 = *(const float4*)(row + 8*l);
    float4 y0 = *(const float4*)(row + 8*l + 4);
    float4 x1 = {0,0,0,0}, y1 = {0,0,0,0};
    bool two = (l < 32);
    if (two) {
        x1 = *(const float4*)(row + 512 + 8*l);
        y1 = *(const float4*)(row + 512 + 8*l + 4);
    }
    float s = x0.x*x0.x + x0.y*x0.y + x0.z*x0.z + x0.w*x0.w
            + y0.x*y0.x + y0.y*y0.y + y0.z*y0.z + y0.w*y0.w;
    if (two) s += x1.x*x1.x + x1.y*x1.y + x1.z*x1.z + x1.w*x1.w
                + y1.x*y1.x + y1.y*y1.y + y1.z*y1.z + y1.w*y1.w;
    #pragma unroll
    for (int off = 32; off; off >>= 1) s += __shfl_xor(s, off);
    float inv = 1.0f / (sqrtf(s) + 1e-6f);

    int kslot = l & 3;
    int lane  = kslot*16 + rlo;
    {   // chunk 0: e0 = 8l, s-step = l>>2
        int st = l >> 2;
        float a[8] = {x0.x, x0.y, x0.z, x0.w, y0.x, y0.y, y0.z, y0.w};
        ushort8v hh, ll;
        #pragma unroll
        for (int j = 0; j < 8; j++) {
            float v = a[j] * inv;
            hh[j] = f2bf(v);
            ll[j] = f2bf(v - bf2f(hh[j]));
        }
        g_tf[tfidx(b, th, st, 0, ct, lane)] = hh;
        g_tf[tfidx(b, th, st, 1, ct, lane)] = ll;
    }
    if (two) {  // chunk 1: e0 = 512+8l, s-step = 16 + (l>>2)
        int st = 16 + (l >> 2);
        float a[8] = {x1.x, x1.y, x1.z, x1.w, y1.x, y1.y, y1.z, y1.w};
        ushort8v hh, ll;
        #pragma unroll
        for (int j = 0; j < 8; j++) {
            float v = a[j] * inv;
            hh[j] = f2bf(v);
            ll[j] = f2bf(v - bf2f(hh[j]));
        }
        g_tf[tfidx(b, th, st, 0, ct, lane)] = hh;
        g_tf[tfidx(b, th, st, 1, ct, lane)] = ll;
    }
}

// ---------------- K2 v9 (FINAL): BK=64 (12 steps), 2-buf 1-ahead + counted vmcnt(4) drain ----------------
// Best verified configuration (68.9us total, round 7). Ten-experiment ledger: MFMA -25%,
// LDS -50%, occupancy x4, conv-ahead, barriers /2, depth-2 A prefetch, global-B, setprio
// all null or negative; all pipes <=40% busy. This structure is at its measured floor.
// Drain proof: end of step S waits `vmcnt(4) lgkmcnt(0)` before the barrier. In-order
// vmcnt: outstanding = STAGE(S+1) (8 loads, issued first) + A(S+1) (4, issued after) ->
// vmcnt(4) drains exactly the STAGE across all waves; A loads stay in flight over the
// barrier. Numerics: 3-pass bf16x3 MFMA (hh, lh, hl; al x bl term ~1e-7 rel, below the
// reference's own fp32 accumulation noise); conv order over k-blocks = 2S,2S+1 = 0..23.
__global__ __launch_bounds__(256) void krel(const float* __restrict__ vis) {
    int bid = blockIdx.x;
    int lid = (bid & 7) * 64 + (bid >> 3);   // XCD-grouped logical id (bijective, 512 = 8x64)
    int b   = lid >> 5;
    int mt  = (lid >> 1) & 15;
    int th  = lid & 1;
    int t   = threadIdx.x;
    int w   = t >> 6, l = t & 63;

    __shared__ __align__(16) ushort8v Bfrag[2][2][2][8][64];  // [buf][sub-k][hi/lo][ct][lane], 64KB

    f32x4 acc[8];
    #pragma unroll
    for (int ct = 0; ct < 8; ct++) acc[ct] = (f32x4){0.f, 0.f, 0.f, 0.f};

    // A fragment: row mt*64 + w*16 + (l&15), k-slot (l>>4)*8
    int arow = mt*64 + w*16 + (l & 15);
    int akq  = (l >> 4) * 8;
    const float* Ap = vis + ((size_t)(b*NN + arow))*ND + akq;

    // B staging: wave w issues chunks c = w*8..w*8+7; c -> (sub = c>>4, h = (c>>3)&1, ct = c&7)
    const ushort8v* Bbase = g_tf + tfidx(b, th, 0, 0, 0, 0);

    #define STAGE(S, P)                                                          \
        {                                                                        \
            _Pragma("unroll")                                                    \
            for (int q = 0; q < 8; q++) {                                        \
                int c   = w*8 + q;                                               \
                int sub = c >> 4, h = (c >> 3) & 1, ct = c & 7;                  \
                const ushort8v* gsrc = Bbase + (((size_t)((S)*2 + sub)*2 + h)*8 + ct)*64 + l; \
                __builtin_amdgcn_global_load_lds(                                \
                    (const __attribute__((address_space(1))) void*)gsrc,         \
                    (__attribute__((address_space(3))) void*)&Bfrag[P][sub][h][ct][0],\
                    16, 0, 0);                                                   \
            }                                                                    \
        }

    #define CONV(AX, AY, AH, AL, SS)                                             \
        {                                                                        \
            float av_[8] = {AX.x, AX.y, AX.z, AX.w, AY.x, AY.y, AY.z, AY.w};     \
            ushort8v hh_, ll_;                                                   \
            _Pragma("unroll")                                                    \
            for (int j = 0; j < 8; j++) {                                        \
                hh_[j] = f2bf(av_[j]);                                           \
                ll_[j] = f2bf(av_[j] - bf2f(hh_[j]));                            \
                SS = fmaf(av_[j], av_[j], SS);                                   \
            }                                                                    \
            AH = *(short8*)&hh_;                                                 \
            AL = *(short8*)&ll_;                                                 \
        }

    // prologue: STAGE step 0 into buf 0; A(0) regs (both sub-k); full drain once
    float4 a0x = *(const float4*)(Ap);
    float4 a0y = *(const float4*)(Ap + 4);
    float4 a1x = *(const float4*)(Ap + 32);
    float4 a1y = *(const float4*)(Ap + 36);
    STAGE(0, 0);
    __syncthreads();
    float ss = 0.f;

    for (int S = 0; S < 12; S++) {
        int p = S & 1;
        // issue step-(S+1) B loads FIRST (8 VMEM; drained by this step's vmcnt(4))
        if (S < 11) STAGE(S + 1, (S + 1) & 1);
        asm volatile("" ::: "memory");   // pin STAGE issuance before the A-prefetch below
        // prefetch A(S+1) (4 VMEM, issued after STAGE(S+1); stays in flight over barrier)
        float4 n0x, n0y, n1x, n1y;
        if (S < 11) {
            int k1 = (S + 1) * 64;
            n0x = *(const float4*)(Ap + k1);
            n0y = *(const float4*)(Ap + k1 + 4);
            n1x = *(const float4*)(Ap + k1 + 32);
            n1y = *(const float4*)(Ap + k1 + 36);
        }
        // convert A regs -> hi/lo fragments + sumsq; sub-k0 then sub-k1
        // (= k-blocks 2S, 2S+1: identical per-lane ss chain to the 24-step version)
        short8 ah0, al0, ah1, al1;
        CONV(a0x, a0y, ah0, al0, ss);
        CONV(a1x, a1y, ah1, al1, ss);
        // MFMA: sub-k0's 8 cts x (hh, lh, hl), then sub-k1's -> same per-output
        // k-block order and pass order as the 24-step version (bit-identical acc)
        #pragma unroll
        for (int ct = 0; ct < 8; ct++) {
            short8 bh = *(const short8*)&Bfrag[p][0][0][ct][l];
            short8 bl = *(const short8*)&Bfrag[p][0][1][ct][l];
            acc[ct] = __builtin_amdgcn_mfma_f32_16x16x32_bf16(ah0, bh, acc[ct], 0, 0, 0);
            acc[ct] = __builtin_amdgcn_mfma_f32_16x16x32_bf16(al0, bh, acc[ct], 0, 0, 0);
            acc[ct] = __builtin_amdgcn_mfma_f32_16x16x32_bf16(ah0, bl, acc[ct], 0, 0, 0);
        }
        #pragma unroll
        for (int ct = 0; ct < 8; ct++) {
            short8 bh = *(const short8*)&Bfrag[p][1][0][ct][l];
            short8 bl = *(const short8*)&Bfrag[p][1][1][ct][l];
            acc[ct] = __builtin_amdgcn_mfma_f32_16x16x32_bf16(ah1, bh, acc[ct], 0, 0, 0);
            acc[ct] = __builtin_amdgcn_mfma_f32_16x16x32_bf16(al1, bh, acc[ct], 0, 0, 0);
            acc[ct] = __builtin_amdgcn_mfma_f32_16x16x32_bf16(ah1, bl, acc[ct], 0, 0, 0);
        }
        if (S < 11) { a0x = n0x; a0y = n0y; a1x = n1x; a1y = n1y; }
        if (S < 11) {
            // counted drain: vmcnt(4) waits STAGE(S+1)'s 8 loads (issued before the 4
            // A-prefetch loads; in-order vmcnt) -> ALL waves' buf[(S+1)&1] writes are
            // in LDS before the barrier releases any step-(S+1) reader. A(S+1) loads
            // stay in flight.
            asm volatile("s_waitcnt vmcnt(4) lgkmcnt(0)" ::: "memory");
            __builtin_amdgcn_s_barrier();
            __builtin_amdgcn_sched_barrier(0);
        }
    }
    #undef STAGE
    #undef CONV

    // rowmax over this half's 128 cols (exact; kfinal maxes the 2 halves)
    #pragma unroll
    for (int r = 0; r < 4; r++) {
        float m = acc[0][r];
        #pragma unroll
        for (int ct = 1; ct < 8; ct++) m = fmaxf(m, acc[ct][r]);
        #pragma unroll
        for (int off = 1; off <= 8; off <<= 1) m = fmaxf(m, __shfl_xor(m, off));
        if ((l & 15) == 0)
            g_mrawp[(size_t)(b*NN + mt*64 + w*16 + (l >> 4)*4 + r)*2 + th] = m;
    }

    // vis row sumsq -> invv/diag (same combine tree); only th==0 writes
    ss += __shfl_xor(ss, 16);
    ss += __shfl_xor(ss, 32);
    if (th == 0 && l < 16) {
        int row = mt*64 + w*16 + l;
        float nrm = sqrtf(ss);
        float inv = 1.0f / (nrm + 1e-6f);
        g_invv[b*NN + row] = inv;
        float dd = nrm * inv;
        g_diagv[b*NN + row] = dd * dd;
    }
}

// ---------------- K3: prep + reg-sort top-64 + MFMA Gram + single-wave greedy + gather ----------------
__global__ __launch_bounds__(1024) void kfinal(const float* __restrict__ vis,
                                               float* __restrict__ out) {
    int b = blockIdx.x;
    int t = threadIdx.x;
    int w = t >> 6, l = t & 63;

    __shared__ u64   s_key[NN];
    __shared__ float s_reln[NN];
    __shared__ __align__(16) unsigned short Chi[NC][392], Clo[NC][392];  // K-chunk 384 + pad
    __shared__ float s_S[NC*65];
    __shared__ int   s_sel[NSEL], s_srt[NSEL];
    __shared__ float s_mn[16], s_mx[16], s_b2[2];

    // ---- prep: relevance minmax-normalize, di2s0, key (1 elem/thread) ----
    float m0 = g_mrawp[(size_t)(b*NN + t)*2 + 0];
    float m1 = g_mrawp[(size_t)(b*NN + t)*2 + 1];
    float iv = g_invv[b*NN + t], dd = g_diagv[b*NN + t];
    float rr = fmaxf(m0, m1) * iv;
    float lmin = rr, lmax = rr;
    #pragma unroll
    for (int off = 32; off; off >>= 1) {
        lmin = fminf(lmin, __shfl_xor(lmin, off));
        lmax = fmaxf(lmax, __shfl_xor(lmax, off));
    }
    if (l == 0) { s_mn[w] = lmin; s_mx[w] = lmax; }
    __syncthreads();
    if (t == 0) {
        float mn = s_mn[0], mx = s_mx[0];
        #pragma unroll
        for (int q = 1; q < 16; q++) { mn = fminf(mn, s_mn[q]); mx = fmaxf(mx, s_mx[q]); }
        s_b2[0] = mn; s_b2[1] = mx;
    }
    __syncthreads();
    float mn = s_b2[0], mx = s_b2[1];
    float den = mx - mn + 1e-6f;
    float rn = (rr - mn + 1e-6f) / den;
    float d0 = rn * rn * dd;
    s_reln[t] = rn;
    u64 kreg = ((u64)(~__float_as_uint(d0)) << 10) | (unsigned)t;

    // ---- per-wave in-register bitonic sort (ascending key = descending d0) ----
    #pragma unroll
    for (int k = 2; k <= 64; k <<= 1) {
        #pragma unroll
        for (int j = k >> 1; j > 0; j >>= 1) {
            u64 part = __shfl_xor(kreg, j);
            bool takeMin = ((l & k) == 0) == ((l & j) == 0);
            kreg = takeMin ? (kreg < part ? kreg : part) : (kreg < part ? part : kreg);
        }
    }
    // ---- symmetric tournament merge: 4 rounds, every wave ends with global top-64 ----
    #pragma unroll
    for (int rnd = 0; rnd < 4; rnd++) {
        int dstp = 8 >> rnd;
        s_key[w*64 + l] = kreg;
        __syncthreads();
        u64 other = s_key[(w ^ dstp)*64 + (63 - l)];
        u64 m = (kreg < other) ? kreg : other;     // 64 smallest of union (bitonic)
        #pragma unroll
        for (int j = 32; j > 0; j >>= 1) {         // ascending clean
            u64 part = __shfl_xor(m, j);
            bool takeMin = ((l & j) == 0);
            m = takeMin ? (m < part ? m : part) : (m < part ? part : m);
        }
        kreg = m;
        __syncthreads();
    }

    // lane l of every wave: l-th best candidate
    int   gid = (int)(kreg & 1023u);
    float d0v = __uint_as_float(~(unsigned)(kreg >> 10));

    // ---- Gram S = vn_c . vn_c^T via bf16x3 MFMA, 2 chunks of K=384 ----
    f32x4 acc = (f32x4){0.f, 0.f, 0.f, 0.f};
    int ar0 = (w >> 2) * 16, bc0 = (w & 3) * 16;
    int cr  = (w << 2) + (l >> 4);                 // candidate row this thread stages
    int sgid = __shfl(gid, cr);
    float sc = g_invv[b*NN + sgid];
    const float* srcrow = vis + (size_t)(b*NN + sgid)*ND + (l & 15)*24;

    for (int c = 0; c < 2; c++) {
        __syncthreads();
        int kb = (l & 15) * 24;
        #pragma unroll
        for (int q = 0; q < 3; q++) {
            float4 x = *(const float4*)(srcrow + c*384 + q*8);
            float4 y = *(const float4*)(srcrow + c*384 + q*8 + 4);
            float av[8] = {x.x, x.y, x.z, x.w, y.x, y.y, y.z, y.w};
            ushort8v hh, ll;
            #pragma unroll
            for (int j = 0; j < 8; j++) {
                float vv = av[j] * sc;
                hh[j] = f2bf(vv);
                ll[j] = f2bf(vv - bf2f(hh[j]));
            }
            *(ushort8v*)&Chi[cr][kb + q*8] = hh;
            *(ushort8v*)&Clo[cr][kb + q*8] = ll;
        }
        __syncthreads();
        #pragma unroll
        for (int ks = 0; ks < 12; ks++) {
            int ko = ks*32 + (l >> 4)*8;
            short8 ah = *(const short8*)&Chi[ar0 + (l & 15)][ko];
            short8 al = *(const short8*)&Clo[ar0 + (l & 15)][ko];
            short8 bh = *(const short8*)&Chi[bc0 + (l & 15)][ko];
            short8 bl = *(const short8*)&Clo[bc0 + (l & 15)][ko];
            acc = __builtin_amdgcn_mfma_f32_16x16x32_bf16(ah, bh, acc, 0, 0, 0);
            acc = __builtin_amdgcn_mfma_f32_16x16x32_bf16(al, bh, acc, 0, 0, 0);
            acc = __builtin_amdgcn_mfma_f32_16x16x32_bf16(ah, bl, acc, 0, 0, 0);
        }
    }
    #pragma unroll
    for (int r = 0; r < 4; r++)
        s_S[(ar0 + (l >> 4)*4 + r)*65 + bc0 + (l & 15)] = acc[r];
    __syncthreads();

    // ---- single-wave greedy: lane = candidate, zero barriers, all state in registers ----
    if (w == 0) {
        float di  = d0v;
        int   gd  = gid;
        float rel = s_reln[gid];
        float ownc[NSEL];
        #pragma unroll
        for (int i = 0; i < NSEL; i++) {
            float vq = fmaxf(di, 1e-12f);
            int   gq = gd;
            int   cq = l;
            #pragma unroll
            for (int off = 32; off; off >>= 1) {
                float vo = __shfl_xor(vq, off);
                int   go = __shfl_xor(gq, off);
                int   co = __shfl_xor(cq, off);
                if (vo > vq || (vo == vq && go < gq)) { vq = vo; gq = go; cq = co; }
            }
            float dj   = __shfl(di, cq);
            float relj = __shfl(rel, cq);
            float denom = sqrtf(fmaxf(dj, 1e-12f)) + 1e-8f;
            if (l == 0) s_sel[i] = gq;

            float cov = 0.f;
            #pragma unroll
            for (int q = 0; q < i; q++)
                cov = fmaf(ownc[q], __shfl(ownc[q], cq), cov);

            float sim = s_S[l*65 + cq];
            float kj  = rel * relj * sim;
            float eis = (kj - cov) / denom;
            ownc[i] = eis;
            di = di - eis * eis;
            if (l == cq) di = -__builtin_inff();
        }
    }
    __syncthreads();

    // ---- sort selected indices; wave w gathers output row w ----
    if (t == 0) {
        int vv[16];
        #pragma unroll
        for (int q = 0; q < 16; q++) vv[q] = s_sel[q];
        for (int a = 1; a < 16; a++) {
            int key = vv[a]; int p2 = a - 1;
            while (p2 >= 0 && vv[p2] > key) { vv[p2+1] = vv[p2]; p2--; }
            vv[p2+1] = key;
        }
        #pragma unroll
        for (int q = 0; q < 16; q++) s_srt[q] = vv[q];
    }
    __syncthreads();
    {
        int idx = s_srt[w];
        const float* src = vis + (size_t)(b*NN + idx)*ND + l*12;
        float*       dst = out + (size_t)(b*NSEL + w)*ND + l*12;
        float4 x = *(const float4*)(src);
        float4 y = *(const float4*)(src + 4);
        float4 z = *(const float4*)(src + 8);
        *(float4*)(dst)     = x;
        *(float4*)(dst + 4) = y;
        *(float4*)(dst + 8) = z;
    }
}

extern "C" void kernel_launch(void* const* d_in, const int* in_sizes, int n_in,
                              void* d_out, int out_size, void* d_ws, size_t ws_size,
                              hipStream_t stream) {
    (void)in_sizes; (void)n_in; (void)d_ws; (void)ws_size; (void)out_size;
    const float* vis = (const float*)d_in[0];
    const float* txt = (const float*)d_in[1];
    float* out = (float*)d_out;

    ktxt  <<<dim3((NB*NT)/4), dim3(256),  0, stream>>>(txt);
    krel  <<<dim3(512),       dim3(256),  0, stream>>>(vis);
    kfinal<<<dim3(NB),        dim3(1024), 0, stream>>>(vis, out);
}